// Round 12
// baseline (201.188 us; speedup 1.0000x reference)
//
#include <hip/hip_runtime.h>
#include <hip/hip_bf16.h>
#include <math.h>

// STGCN fused, MFMA version, round 12: 32x32x16 MFMA for the big stages.
// Round 11 (138.7us): VALUBusy 47% dominated by PER-JOB overhead (addressing,
// m/TOUT, bias loads, loop bookkeeping) - scales with job count not outputs.
// Fix: stage1/cheb1/stage3/cheb2 -> mfma_f32_32x32x16_bf16 (2x MAC/instr):
// wave-jobs on those stages 128 -> 28, MFMA instrs 912 -> ~650, ds_reads ~2x
// fewer. Operand swap kept (weights=A, acts=B): C gives each lane 16 outputs
// of ONE m in 4 contiguous-co quads -> 4 ushort4 stores. Weight ws layout
// unchanged. stage4 (balance) + stage6/mlp (N=16) stay 16x16 as in r11.

namespace {

constexpr int NT = 512;               // 8 waves
constexpr int NP = 32;                // (b,n) pairs per block (same n)
constexpr float INV_STD = 0.9999950000374997f; // 1/sqrt(1+1e-5)

typedef __attribute__((ext_vector_type(8)))  short bf16x8;
typedef __attribute__((ext_vector_type(4)))  float f32x4;
typedef __attribute__((ext_vector_type(16))) float f32x16;

// d_ws layout (bf16 element offsets). All sections 16B-aligned (off%8==0).
constexpr int OFF_CHEB_A = 0;         // [32co][32k]
constexpr int OFF_CHEB_B = 1024;      // [32co][32k]
constexpr int OFF_A2     = 2048;      // P,Q,R x [64co][96k]
constexpr int OFF_B1     = 20480;     // P,Q,R x [32co][192k]
constexpr int OFF_B2     = 38912;     // P,Q,R x [16co][96k]
constexpr int OFF_S1B    = 43520;     // P,Q,R x [32co][32k] (zero-padded K)
constexpr int OFF_W1     = 46592;     // 113 x [64h][32k]
constexpr int OFF_W2     = 278016;    // 113 x [3o][64k]
// total ws bytes needed: (278016 + 21696) * 2 = 599,424

__device__ __forceinline__ unsigned short f2bf(float f){   // RNE f32->bf16 (prep)
  unsigned int u = __float_as_uint(f);
  u += 0x7fffu + ((u >> 16) & 1u);
  return (unsigned short)(u >> 16);
}
__device__ __forceinline__ unsigned short f2bf_fast(float f){  // native RNE
  return __bfloat16_as_ushort(__float2bfloat16(f));
}
__device__ __forceinline__ f32x4 bcast(float v){ f32x4 r; r[0]=v; r[1]=v; r[2]=v; r[3]=v; return r; }

struct Params {
  const float *x;
  const float *awp,*abp,*awq,*abq,*awr,*abr,*acw,*acb;
  const float *awp2,*abp2,*awq2,*abq2,*awr2,*abr2,*ag,*abeta;
  const float *bwp,*bbp,*bwq,*bbq,*bwr,*bbr,*bcw,*bcb;
  const float *bwp2,*bbp2,*bwq2,*bbq2,*bwr2,*bbr2,*bg,*bbeta;
  const float *w1,*b1,*w2,*b2;
  float *out;
};

// ---------------- prep: one-time weight transpose/convert into ws ----------------
__global__ void stgcn_prep(const Params p, unsigned short* __restrict__ W)
{
  int e = blockIdx.x*256 + threadIdx.x;
  if (e < 2048){                                    // cheb a/b [ci][co] -> [co][ci]
    const float* src = (e < 1024) ? p.acw : p.bcw;
    const int j = e & 1023, co = j >> 5, k = j & 31;
    W[e] = f2bf(src[k*32 + co]);
    return;
  }
  e -= 2048;
  if (e < 18432){                                   // a2: 3 x [64co][96k]
    const int mat = e / 6144, j = e % 6144, co = j / 96, k = j % 96;
    const float* src = mat==0 ? p.awp2 : (mat==1 ? p.awq2 : p.awr2);
    W[OFF_A2 + e] = f2bf(src[k*64 + co]);
    return;
  }
  e -= 18432;
  if (e < 18432){                                   // b1: 3 x [32co][192k]
    const int mat = e / 6144, j = e % 6144, co = j / 192, k = j % 192;
    const float* src = mat==0 ? p.bwp : (mat==1 ? p.bwq : p.bwr);
    W[OFF_B1 + e] = f2bf(src[k*32 + co]);
    return;
  }
  e -= 18432;
  if (e < 4608){                                    // b2: 3 x [16co][96k]
    const int mat = e / 1536, j = e % 1536, co = j / 96, k = j % 96;
    const float* src = mat==0 ? p.bwp2 : (mat==1 ? p.bwq2 : p.bwr2);
    W[OFF_B2 + e] = f2bf(src[k*16 + co]);
    return;
  }
  e -= 4608;
  if (e < 3072){                                    // s1: 3 x [32co][32k], k=tt*8+ci
    const int mat = e / 1024, j = e % 1024, co = j >> 5, k = j & 31;
    const int tt = k >> 3, ci = k & 7;
    const float* src = mat==0 ? p.awp : (mat==1 ? p.awq : p.awr);
    W[OFF_S1B + e] = (ci < 4 && tt < 3) ? f2bf(src[(tt*4+ci)*32 + co])
                                        : (unsigned short)0;
    return;
  }
  e -= 3072;
  if (e < 231424){ W[OFF_W1 + e] = f2bf(p.w1[e]); return; }  // [n][h][f] already B^T
  e -= 231424;
  if (e < 21696){ W[OFF_W2 + e] = f2bf(p.w2[e]); }           // [n][o][k] already B^T
}

// ---------------- 32x32x16 MFMA stage (operand-swapped) ----------------
// A = weights: lane row co = Ntile*32 + (l&31), k = ks*16 + (l>>5)*8 + j.
// B = acts: lane col m = Mtile*32 + (l&31), same k mapping.
// C: col = l&31 = m; row co = 8g + 4*(l>>5) + r for reg = 4g+r ->
// each lane: 16 outputs of ONE m, 4 contiguous-co quads -> 4 ushort4 stores.
// MODE: 0 = stage1 (padded 8-elem t-slots, k = tt*8+ci, tt = 2ks+hi);
//       1 = flat K within row (cheb);  2 = conv CIN=32 (k = kt*32+ci).
// EPI: 0 relu(acc+b); 1 relu(P*sig(Q)+R); 2 = EPI1 then relu(v*bn+bt).
template<int TOUT, int NK, int MODE, int RSTI, int PSTI, int RSTO, int PSTO,
         int KP, int EPI, bool RELOAD, int COUT>
__device__ __forceinline__ void mfma_stage32(
    const unsigned short* __restrict__ aB,
    const unsigned short* __restrict__ gW,
    unsigned short* __restrict__ oB,
    const float* __restrict__ gb0, const float* __restrict__ gb1,
    const float* __restrict__ gb2,
    const int Mtile, const int Ntile, const int lr, const int hi,
    const float bnsc, const float bnbt)
{
  const unsigned short* wbase = gW + (Ntile*32 + lr)*KP + hi*8;
  const int cb = Ntile*32 + hi*4;          // bias/store col base (+8g)
  f32x16 aP, aQ, aR;
  #pragma unroll
  for (int g = 0; g < 4; ++g){
    const f32x4 b0 = *reinterpret_cast<const f32x4*>(gb0 + cb + g*8);
    #pragma unroll
    for (int r = 0; r < 4; ++r) aP[g*4+r] = b0[r];
    if constexpr (EPI >= 1){
      const f32x4 b1 = *reinterpret_cast<const f32x4*>(gb1 + cb + g*8);
      const f32x4 b2 = *reinterpret_cast<const f32x4*>(gb2 + cb + g*8);
      #pragma unroll
      for (int r = 0; r < 4; ++r){ aQ[g*4+r] = b1[r]; aR[g*4+r] = b2[r]; }
    }
  }
  const int m  = Mtile*32 + lr;
  const int pr = m / TOUT;
  const int t  = m - pr*TOUT;

  auto kbody = [&](const int ks){
    const bf16x8 fp = *reinterpret_cast<const bf16x8*>(wbase + ks*16);
    bf16x8 fq, fr;
    if constexpr (EPI >= 1){
      fq = *reinterpret_cast<const bf16x8*>(wbase +   COUT*KP + ks*16);
      fr = *reinterpret_cast<const bf16x8*>(wbase + 2*COUT*KP + ks*16);
    }
    int elem;
    if constexpr (MODE == 0) elem = pr*PSTI + (t + 2*ks + hi)*RSTI;
    else if constexpr (MODE == 1) elem = pr*PSTI + t*RSTI + ks*16 + hi*8;
    else elem = pr*PSTI + (t + (ks>>1))*RSTI + (ks&1)*16 + hi*8;
    const bf16x8 a = *reinterpret_cast<const bf16x8*>(aB + elem);
    aP = __builtin_amdgcn_mfma_f32_32x32x16_bf16(fp, a, aP, 0, 0, 0);
    if constexpr (EPI >= 1){
      aQ = __builtin_amdgcn_mfma_f32_32x32x16_bf16(fq, a, aQ, 0, 0, 0);
      aR = __builtin_amdgcn_mfma_f32_32x32x16_bf16(fr, a, aR, 0, 0, 0);
    }
  };
  if constexpr (RELOAD){
    #pragma unroll 1
    for (int ks = 0; ks < NK; ++ks) kbody(ks);
  } else {
    #pragma unroll
    for (int ks = 0; ks < NK; ++ks) kbody(ks);
  }

  #pragma unroll
  for (int g = 0; g < 4; ++g){
    unsigned short pv[4];
    #pragma unroll
    for (int r = 0; r < 4; ++r){
      float v;
      if constexpr (EPI == 0) v = fmaxf(aP[g*4+r], 0.f);
      else {
        const float sig = 1.f/(1.f + __expf(-aQ[g*4+r]));
        v = fmaxf(fmaf(aP[g*4+r], sig, aR[g*4+r]), 0.f);
        if constexpr (EPI == 2) v = fmaxf(fmaf(v, bnsc, bnbt), 0.f);
      }
      pv[r] = f2bf_fast(v);
    }
    ushort4 pk; pk.x=pv[0]; pk.y=pv[1]; pk.z=pv[2]; pk.w=pv[3];
    *reinterpret_cast<ushort4*>(oB + pr*PSTO + t*RSTO + cb + g*8) = pk;
  }
}

// ---------------- 16x16x32 MFMA stage (operand-swapped, r11) ----------------
template<int TOUT, int CIN, int COUT, int NK, int RSTI, int PSTI, int RSTO, int PSTO,
         int KP, int EPI, int MJOBS, int MSTEP, bool RELOADB>
__device__ __forceinline__ void mfma_stage(const unsigned short* __restrict__ aB,
    const unsigned short* __restrict__ gW, unsigned short* __restrict__ oB,
    const float* __restrict__ gb0, const float* __restrict__ gb1,
    const float* __restrict__ gb2,
    const int Mtile0, const int Ntile, const int lm, const int lk,
    const float bnsc, const float bnbt)
{
  const unsigned short* wbase = gW + (Ntile*16 + lm)*KP + lk*8;
  const int colbase = Ntile*16 + lk*4;
  bf16x8 wp[NK], wq[NK], wr[NK];
  if constexpr (!RELOADB){
    #pragma unroll
    for (int ks = 0; ks < NK; ++ks){
      wp[ks] = *reinterpret_cast<const bf16x8*>(wbase + ks*32);
      if constexpr (EPI >= 1){
        wq[ks] = *reinterpret_cast<const bf16x8*>(wbase +   COUT*KP + ks*32);
        wr[ks] = *reinterpret_cast<const bf16x8*>(wbase + 2*COUT*KP + ks*32);
      }
    }
  }
  const f32x4 b0v = *reinterpret_cast<const f32x4*>(gb0 + colbase);
  f32x4 b1v, b2v;
  if constexpr (EPI >= 1){
    b1v = *reinterpret_cast<const f32x4*>(gb1 + colbase);
    b2v = *reinterpret_cast<const f32x4*>(gb2 + colbase);
  }

  #pragma unroll 1
  for (int j = 0; j < MJOBS; ++j){
    const int m  = (Mtile0 + j*MSTEP)*16 + lm;
    const int pr = m / TOUT;
    const int t  = m - pr*TOUT;
    f32x4 aP = b0v, aQ, aR;
    if constexpr (EPI >= 1){ aQ = b1v; aR = b2v; }
    #pragma unroll
    for (int ks = 0; ks < NK; ++ks){
      bf16x8 fp, fq, fr;
      if constexpr (RELOADB){
        fp = *reinterpret_cast<const bf16x8*>(wbase + ks*32);
        if constexpr (EPI >= 1){
          fq = *reinterpret_cast<const bf16x8*>(wbase +   COUT*KP + ks*32);
          fr = *reinterpret_cast<const bf16x8*>(wbase + 2*COUT*KP + ks*32);
        }
      } else {
        fp = wp[ks];
        if constexpr (EPI >= 1){ fq = wq[ks]; fr = wr[ks]; }
      }
      int elem;
      if constexpr (CIN == 32) elem = pr*PSTI + (t + ks)*RSTI + lk*8;
      else                     elem = pr*PSTI + (t + (ks>>1))*RSTI + (ks&1)*32 + lk*8;
      const bf16x8 a = *reinterpret_cast<const bf16x8*>(aB + elem);
      aP = __builtin_amdgcn_mfma_f32_16x16x32_bf16(fp, a, aP, 0, 0, 0);
      if constexpr (EPI >= 1){
        aQ = __builtin_amdgcn_mfma_f32_16x16x32_bf16(fq, a, aQ, 0, 0, 0);
        aR = __builtin_amdgcn_mfma_f32_16x16x32_bf16(fr, a, aR, 0, 0, 0);
      }
    }
    ushort4 pk;
    unsigned short pv[4];
    #pragma unroll
    for (int r = 0; r < 4; ++r){
      float v;
      if constexpr (EPI == 0) v = fmaxf(aP[r], 0.f);
      else {
        const float sig = 1.f/(1.f + __expf(-aQ[r]));
        v = fmaxf(fmaf(aP[r], sig, aR[r]), 0.f);
        if constexpr (EPI == 2) v = fmaxf(fmaf(v, bnsc, bnbt), 0.f);
      }
      pv[r] = f2bf_fast(v);
    }
    pk.x = pv[0]; pk.y = pv[1]; pk.z = pv[2]; pk.w = pv[3];
    *reinterpret_cast<ushort4*>(oB + pr*PSTO + t*RSTO + colbase) = pk;
  }
}

// ---------------- stage4 (K=192): 16x16, k-outer / j-inner, swapped ----------------
__device__ __forceinline__ void mfma_stage4(const unsigned short* __restrict__ aB,
    const unsigned short* __restrict__ gW, unsigned short* __restrict__ oB,
    const float* __restrict__ gb0, const float* __restrict__ gb1,
    const float* __restrict__ gb2,
    const int Mtile0, const int Ntile, const int lm, const int lk)
{
  const unsigned short* wbase = gW + (Ntile*16 + lm)*192 + lk*8;
  const int colbase = Ntile*16 + lk*4;
  f32x4 aP[2], aQ[2], aR[2];
  {
    const f32x4 b0v = *reinterpret_cast<const f32x4*>(gb0 + colbase);
    const f32x4 b1v = *reinterpret_cast<const f32x4*>(gb1 + colbase);
    const f32x4 b2v = *reinterpret_cast<const f32x4*>(gb2 + colbase);
    #pragma unroll
    for (int j=0;j<2;++j){ aP[j]=b0v; aQ[j]=b1v; aR[j]=b2v; }
  }
  #pragma unroll 1
  for (int kb = 0; kb < 2; ++kb){
    bf16x8 wp[3], wq[3], wr[3];
    #pragma unroll
    for (int s = 0; s < 3; ++s){
      const int ks = kb*3 + s;
      wp[s] = *reinterpret_cast<const bf16x8*>(wbase +         ks*32);
      wq[s] = *reinterpret_cast<const bf16x8*>(wbase +  6144 + ks*32); // 32*192
      wr[s] = *reinterpret_cast<const bf16x8*>(wbase + 12288 + ks*32);
    }
    #pragma unroll
    for (int j = 0; j < 2; ++j){
      const int m  = (Mtile0 + j*4)*16 + lm;
      const int pr = m >> 2, t = m & 3;
      #pragma unroll
      for (int s = 0; s < 3; ++s){
        const int ks = kb*3 + s;
        const int elem = pr*432 + (t + (ks>>1))*72 + (ks&1)*32 + lk*8;
        const bf16x8 a = *reinterpret_cast<const bf16x8*>(aB + elem);
        aP[j] = __builtin_amdgcn_mfma_f32_16x16x32_bf16(wp[s], a, aP[j], 0,0,0);
        aQ[j] = __builtin_amdgcn_mfma_f32_16x16x32_bf16(wq[s], a, aQ[j], 0,0,0);
        aR[j] = __builtin_amdgcn_mfma_f32_16x16x32_bf16(wr[s], a, aR[j], 0,0,0);
      }
    }
  }
  #pragma unroll
  for (int j = 0; j < 2; ++j){
    const int m  = (Mtile0 + j*4)*16 + lm;
    const int pr = m >> 2, t = m & 3;
    ushort4 pk;
    unsigned short pv[4];
    #pragma unroll
    for (int r = 0; r < 4; ++r){
      const float sig = 1.f/(1.f + __expf(-aQ[j][r]));
      pv[r] = f2bf_fast(fmaxf(fmaf(aP[j][r], sig, aR[j][r]), 0.f));
    }
    pk.x = pv[0]; pk.y = pv[1]; pk.z = pv[2]; pk.w = pv[3];
    *reinterpret_cast<ushort4*>(oB + pr*160 + t*40 + colbase) = pk;
  }
}

// ---------------- main fused kernel ----------------
// LDS: one 48,128 B arena. bufA = smem[0..13823], bufB = smem[13824..24063],
// sxb ALIASES bufB (dead before cheb1 writes bufB).
// launch_bounds(512,4): f32x16 accs x3 + frags ~ 90-110 VGPR, no spill.
__global__ __launch_bounds__(NT, 4) void stgcn_main(const Params p,
    const unsigned short* __restrict__ W)
{
  __shared__ __align__(16) unsigned short smem[24064];   // 48,128 B
  unsigned short* const bufA = smem;            // 13824 elems (27648 B)
  unsigned short* const bufB = smem + 13824;    // 10240 elems (20480 B)
  unsigned short* const sxb  = bufB;            // 2816 elems, dead before cheb1

  const int tid = threadIdx.x;
  const int l   = tid & 63;
  const int wid = tid >> 6;     // 0..7
  const int lm  = l & 15;
  const int lk  = l >> 4;
  const int lr  = l & 31;       // 32x32 row/col
  const int hi  = l >> 5;       // 32x32 k-half
  const int n   = blockIdx.x >> 5;          // b-fastest: 32 consecutive blocks
  const int b0  = (blockIdx.x & 31) * NP;   // share one n (weights L2-hot)

  // x tile: one 8B chunk per (pr, half-slot); even chunks get bf16(x), odd zeros
  for (int i = tid; i < NP*22; i += NT){
    const int pr = i / 22, c = i - pr*22;
    const int t  = c >> 1;
    unsigned short v0=0,v1=0,v2=0,v3=0;
    if (!(c & 1) && t < 10){
      const float4 xf = *reinterpret_cast<const float4*>(
          &p.x[(size_t)(((b0+pr)*10 + t)*113 + n)*4]);
      v0 = f2bf_fast(xf.x); v1 = f2bf_fast(xf.y);
      v2 = f2bf_fast(xf.z); v3 = f2bf_fast(xf.w);
    }
    ushort4 pk; pk.x=v0; pk.y=v1; pk.z=v2; pk.w=v3;
    *reinterpret_cast<ushort4*>(&sxb[i*4]) = pk;
  }
  __syncthreads();

  // stage1: (10,4)->(8,32) gated conv, K padded 12->32. 32x32: M=256(8) N=32(1)
  mfma_stage32<8, 2, 0, 8,88, 40,320, 32, 1, false, 32>(
      sxb, W+OFF_S1B, bufA, p.abp, p.abq, p.abr, wid, 0, lr, hi, 0.f, 0.f);
  __syncthreads();

  // cheb1: 32x32: M=256(8) N=32(1) K=32 -> bufB (overwrites sxb, now dead)
  mfma_stage32<8, 2, 1, 40,320, 40,320, 32, 0, false, 32>(
      bufA, W+OFF_CHEB_A, bufB, p.acb, p.acb, p.acb, wid, 0, lr, hi, 0.f, 0.f);
  __syncthreads();

  // stage3: (8,32)->(6,64) gated + BN(a). 32x32: M=192(6) N=64(2) K=96 -> 12 jobs
  {
    const float bnsc = INV_STD * p.ag[n], bnbt = p.abeta[n];
    #pragma unroll 1
    for (int rep = 0; rep < 2; ++rep){
      const int j = wid + rep*8;
      if (j < 12)
        mfma_stage32<6, 6, 2, 40,320, 72,432, 96, 2, true, 64>(
            bufB, W+OFF_A2, bufA, p.abp2, p.abq2, p.abr2, j>>1, j&1, lr, hi, bnsc, bnbt);
    }
  }
  __syncthreads();

  // stage4: (6,64)->(4,32) gated. 16x16: M=128(8) N=32(2) K=192 -> bufB
  mfma_stage4(bufA, W+OFF_B1, bufB, p.bbp, p.bbq, p.bbr, wid>>1, wid&1, lm, lk);
  __syncthreads();

  // cheb2: 32x32: M=128(4) N=32(1) K=32 -> bufA
  if (wid < 4){
    mfma_stage32<4, 2, 1, 40,160, 40,160, 32, 0, false, 32>(
        bufB, W+OFF_CHEB_B, bufA, p.bcb, p.bcb, p.bcb, wid, 0, lr, hi, 0.f, 0.f);
  }
  __syncthreads();

  // stage6: (4,32)->(2,16) gated + BN(b). 16x16: M=64(4) N=16(1) K=96 -> bufB (h4)
  if (wid < 4){
    const float bnsc = INV_STD * p.bg[n], bnbt = p.bbeta[n];
    mfma_stage<2,32,16,3, 40,160, 16,40, 96, 2, 1,1, false>(
        bufA, W+OFF_B2, bufB, p.bbp2, p.bbq2, p.bbr2, wid, 0, lm, lk, bnsc, bnbt);
  }
  __syncthreads();

  // mlp1: feat(32) -> hid(64). 16x16: M=32(2) N=64(4) K=32 -> bufA
  mfma_stage<1,32,64,1, 16,40, 16,72, 32, 0, 1,1, false>(
      bufB, W+OFF_W1 + n*2048, bufA, p.b1 + n*64, p.b1, p.b1, wid&1, wid>>1, lm, lk, 0.f, 0.f);
  __syncthreads();

  // mlp2: hid(64) -> 3, swapped 16x16. C: row=o=lk*4+r, col=m=Mtile*16+lm.
  if (wid < 2){
    const unsigned short* WM2 = W + OFF_W2 + n*192;
    const int Mtile = wid;
    const int m = Mtile*16 + lm;
    const int lmo = (lm < 3) ? lm : 0;       // clamp A-row into valid W2 rows
    f32x4 acc = bcast(0.f);
    if (lk == 0){ acc[0]=p.b2[n*3]; acc[1]=p.b2[n*3+1]; acc[2]=p.b2[n*3+2]; }
    #pragma unroll
    for (int ks = 0; ks < 2; ++ks){
      const bf16x8 aw = *reinterpret_cast<const bf16x8*>(WM2 + lmo*64 + ks*32 + lk*8);
      const bf16x8 bh = *reinterpret_cast<const bf16x8*>(bufA + m*72 + ks*32 + lk*8);
      acc = __builtin_amdgcn_mfma_f32_16x16x32_bf16(aw, bh, acc, 0, 0, 0);
    }
    if (lk == 0){
      float* op = p.out + (size_t)((b0 + m)*113 + n)*3;
      op[0] = acc[0]; op[1] = acc[1]; op[2] = acc[2];
    }
  }
}

} // namespace

extern "C" void kernel_launch(void* const* d_in, const int* in_sizes, int n_in,
                              void* d_out, int out_size, void* d_ws, size_t ws_size,
                              hipStream_t stream) {
  (void)in_sizes; (void)n_in; (void)ws_size; (void)out_size;
  Params p;
  p.x     = (const float*)d_in[0];
  // d_in[1] = edge_index (unused: ChebConv K=1 keeps only the identity term)
  p.awp   = (const float*)d_in[2];  p.abp   = (const float*)d_in[3];
  p.awq   = (const float*)d_in[4];  p.abq   = (const float*)d_in[5];
  p.awr   = (const float*)d_in[6];  p.abr   = (const float*)d_in[7];
  p.acw   = (const float*)d_in[8];  p.acb   = (const float*)d_in[9];
  p.awp2  = (const float*)d_in[10]; p.abp2  = (const float*)d_in[11];
  p.awq2  = (const float*)d_in[12]; p.abq2  = (const float*)d_in[13];
  p.awr2  = (const float*)d_in[14]; p.abr2  = (const float*)d_in[15];
  p.ag    = (const float*)d_in[16]; p.abeta = (const float*)d_in[17];
  p.bwp   = (const float*)d_in[18]; p.bbp   = (const float*)d_in[19];
  p.bwq   = (const float*)d_in[20]; p.bbq   = (const float*)d_in[21];
  p.bwr   = (const float*)d_in[22]; p.bbr   = (const float*)d_in[23];
  p.bcw   = (const float*)d_in[24]; p.bcb   = (const float*)d_in[25];
  p.bwp2  = (const float*)d_in[26]; p.bbp2  = (const float*)d_in[27];
  p.bwq2  = (const float*)d_in[28]; p.bbq2  = (const float*)d_in[29];
  p.bwr2  = (const float*)d_in[30]; p.bbr2  = (const float*)d_in[31];
  p.bg    = (const float*)d_in[32]; p.bbeta = (const float*)d_in[33];
  p.w1    = (const float*)d_in[34]; p.b1    = (const float*)d_in[35];
  p.w2    = (const float*)d_in[36]; p.b2    = (const float*)d_in[37];
  p.out   = (float*)d_out;

  unsigned short* W = (unsigned short*)d_ws;   // needs 599,424 bytes

  // prep: 299,712 work items
  stgcn_prep<<<1171, 256, 0, stream>>>(p, W);

  const int tiles = 113 * 32;  // 3616, b fastest within each n
  stgcn_main<<<tiles, NT, 0, stream>>>(p, W);
}

// Round 13
// 145.811 us; speedup vs baseline: 1.3798x; 1.3798x over previous
//
#include <hip/hip_runtime.h>
#include <hip/hip_bf16.h>
#include <math.h>

// STGCN fused, MFMA version, round 13.
// Round 12 (32x32) regressed 138.7->201us: fewer/longer MFMA chains exposed
// dependency latency (both pipes idler). Reverted to round 11 structure.
// Round 11 re-tally: ~680 global weight-frag loads/block x 1KB wave-wide
// through the per-CU L1 data path (~64B/cyc) ~= 45% of wall - the shared
// per-CU pipe that explains occupancy-insensitivity. 432 of those are
// stage3's RELOADB re-loads (9 frags x every M-job). This round: stage3
// preloads its 9 B-frags once per wave and reuses across 6 M-jobs
// (W-loads 432->72), launch_bounds(512,4) for the fatter live set
// (~70 VGPR, r5-proven no-spill). Everything else identical to r11 (138.7us).

namespace {

constexpr int NT = 512;               // 8 waves
constexpr int NP = 32;                // (b,n) pairs per block (same n)
constexpr float INV_STD = 0.9999950000374997f; // 1/sqrt(1+1e-5)

typedef __attribute__((ext_vector_type(8))) short bf16x8;
typedef __attribute__((ext_vector_type(4))) float f32x4;

// d_ws layout (bf16 element offsets). All sections 16B-aligned (off%8==0).
constexpr int OFF_CHEB_A = 0;         // [32co][32k]
constexpr int OFF_CHEB_B = 1024;      // [32co][32k]
constexpr int OFF_A2     = 2048;      // P,Q,R x [64co][96k]
constexpr int OFF_B1     = 20480;     // P,Q,R x [32co][192k]
constexpr int OFF_B2     = 38912;     // P,Q,R x [16co][96k]
constexpr int OFF_S1B    = 43520;     // P,Q,R x [32co][32k] (zero-padded K)
constexpr int OFF_W1     = 46592;     // 113 x [64h][32k]
constexpr int OFF_W2     = 278016;    // 113 x [3o][64k]
// total ws bytes needed: (278016 + 21696) * 2 = 599,424

__device__ __forceinline__ unsigned short f2bf(float f){   // RNE f32->bf16 (prep)
  unsigned int u = __float_as_uint(f);
  u += 0x7fffu + ((u >> 16) & 1u);
  return (unsigned short)(u >> 16);
}
__device__ __forceinline__ unsigned short f2bf_fast(float f){  // native RNE
  return __bfloat16_as_ushort(__float2bfloat16(f));
}
__device__ __forceinline__ f32x4 bcast(float v){ f32x4 r; r[0]=v; r[1]=v; r[2]=v; r[3]=v; return r; }

struct Params {
  const float *x;
  const float *awp,*abp,*awq,*abq,*awr,*abr,*acw,*acb;
  const float *awp2,*abp2,*awq2,*abq2,*awr2,*abr2,*ag,*abeta;
  const float *bwp,*bbp,*bwq,*bbq,*bwr,*bbr,*bcw,*bcb;
  const float *bwp2,*bbp2,*bwq2,*bbq2,*bwr2,*bbr2,*bg,*bbeta;
  const float *w1,*b1,*w2,*b2;
  float *out;
};

// ---------------- prep: one-time weight transpose/convert into ws ----------------
__global__ void stgcn_prep(const Params p, unsigned short* __restrict__ W)
{
  int e = blockIdx.x*256 + threadIdx.x;
  if (e < 2048){                                    // cheb a/b [ci][co] -> [co][ci]
    const float* src = (e < 1024) ? p.acw : p.bcw;
    const int j = e & 1023, co = j >> 5, k = j & 31;
    W[e] = f2bf(src[k*32 + co]);
    return;
  }
  e -= 2048;
  if (e < 18432){                                   // a2: 3 x [64co][96k]
    const int mat = e / 6144, j = e % 6144, co = j / 96, k = j % 96;
    const float* src = mat==0 ? p.awp2 : (mat==1 ? p.awq2 : p.awr2);
    W[OFF_A2 + e] = f2bf(src[k*64 + co]);
    return;
  }
  e -= 18432;
  if (e < 18432){                                   // b1: 3 x [32co][192k]
    const int mat = e / 6144, j = e % 6144, co = j / 192, k = j % 192;
    const float* src = mat==0 ? p.bwp : (mat==1 ? p.bwq : p.bwr);
    W[OFF_B1 + e] = f2bf(src[k*32 + co]);
    return;
  }
  e -= 18432;
  if (e < 4608){                                    // b2: 3 x [16co][96k]
    const int mat = e / 1536, j = e % 1536, co = j / 96, k = j % 96;
    const float* src = mat==0 ? p.bwp2 : (mat==1 ? p.bwq2 : p.bwr2);
    W[OFF_B2 + e] = f2bf(src[k*16 + co]);
    return;
  }
  e -= 4608;
  if (e < 3072){                                    // s1: 3 x [32co][32k], k=tt*8+ci
    const int mat = e / 1024, j = e % 1024, co = j >> 5, k = j & 31;
    const int tt = k >> 3, ci = k & 7;
    const float* src = mat==0 ? p.awp : (mat==1 ? p.awq : p.awr);
    W[OFF_S1B + e] = (ci < 4 && tt < 3) ? f2bf(src[(tt*4+ci)*32 + co])
                                        : (unsigned short)0;
    return;
  }
  e -= 3072;
  if (e < 231424){ W[OFF_W1 + e] = f2bf(p.w1[e]); return; }  // [n][h][f] already B^T
  e -= 231424;
  if (e < 21696){ W[OFF_W2 + e] = f2bf(p.w2[e]); }           // [n][o][k] already B^T
}

// ---------------- generic MFMA stage (operand-swapped) ----------------
// Weights are the A operand (row = co = Ntile*16+lm), activations are B
// (col = m = Mtile*16+lm). Read addresses identical to the unswapped form.
// C: lane holds co = Ntile*16 + lk*4 + r (4 consecutive) for ONE m ->
// epilogue is a single ushort4 store + float4 bias init.
// EPI: 0 = relu(acc+bias); 1 = relu(P*sig(Q)+R); 2 = EPI1 then relu(v*bn+bt).
template<int TOUT, int CIN, int COUT, int NK, int RSTI, int PSTI, int RSTO, int PSTO,
         int KP, int EPI, int MJOBS, int MSTEP, bool RELOADB>
__device__ __forceinline__ void mfma_stage(const unsigned short* __restrict__ aB,
    const unsigned short* __restrict__ gW, unsigned short* __restrict__ oB,
    const float* __restrict__ gb0, const float* __restrict__ gb1,
    const float* __restrict__ gb2,
    const int Mtile0, const int Ntile, const int lm, const int lk,
    const float bnsc, const float bnbt)
{
  const unsigned short* wbase = gW + (Ntile*16 + lm)*KP + lk*8;
  const int colbase = Ntile*16 + lk*4;      // this lane's 4 output channels
  bf16x8 wp[NK], wq[NK], wr[NK];
  if constexpr (!RELOADB){
    #pragma unroll
    for (int ks = 0; ks < NK; ++ks){
      wp[ks] = *reinterpret_cast<const bf16x8*>(wbase + ks*32);
      if constexpr (EPI >= 1){
        wq[ks] = *reinterpret_cast<const bf16x8*>(wbase +   COUT*KP + ks*32);
        wr[ks] = *reinterpret_cast<const bf16x8*>(wbase + 2*COUT*KP + ks*32);
      }
    }
  }
  const f32x4 b0v = *reinterpret_cast<const f32x4*>(gb0 + colbase);
  f32x4 b1v, b2v;
  if constexpr (EPI >= 1){
    b1v = *reinterpret_cast<const f32x4*>(gb1 + colbase);
    b2v = *reinterpret_cast<const f32x4*>(gb2 + colbase);
  }

  #pragma unroll 1
  for (int j = 0; j < MJOBS; ++j){
    const int m  = (Mtile0 + j*MSTEP)*16 + lm;
    const int pr = m / TOUT;
    const int t  = m - pr*TOUT;
    f32x4 aP = b0v, aQ, aR;
    if constexpr (EPI >= 1){ aQ = b1v; aR = b2v; }
    #pragma unroll
    for (int ks = 0; ks < NK; ++ks){
      bf16x8 fp, fq, fr;
      if constexpr (RELOADB){
        fp = *reinterpret_cast<const bf16x8*>(wbase + ks*32);
        if constexpr (EPI >= 1){
          fq = *reinterpret_cast<const bf16x8*>(wbase +   COUT*KP + ks*32);
          fr = *reinterpret_cast<const bf16x8*>(wbase + 2*COUT*KP + ks*32);
        }
      } else {
        fp = wp[ks];
        if constexpr (EPI >= 1){ fq = wq[ks]; fr = wr[ks]; }
      }
      int elem;
      if constexpr (CIN == 32) elem = pr*PSTI + (t + ks)*RSTI + lk*8;
      else                     elem = pr*PSTI + (t + (ks>>1))*RSTI + (ks&1)*32 + lk*8;
      const bf16x8 a = *reinterpret_cast<const bf16x8*>(aB + elem);
      aP = __builtin_amdgcn_mfma_f32_16x16x32_bf16(fp, a, aP, 0, 0, 0);
      if constexpr (EPI >= 1){
        aQ = __builtin_amdgcn_mfma_f32_16x16x32_bf16(fq, a, aQ, 0, 0, 0);
        aR = __builtin_amdgcn_mfma_f32_16x16x32_bf16(fr, a, aR, 0, 0, 0);
      }
    }
    ushort4 pk;
    unsigned short pv[4];
    #pragma unroll
    for (int r = 0; r < 4; ++r){
      float v;
      if constexpr (EPI == 0) v = fmaxf(aP[r], 0.f);
      else {
        const float sig = 1.f/(1.f + __expf(-aQ[r]));
        v = fmaxf(fmaf(aP[r], sig, aR[r]), 0.f);
        if constexpr (EPI == 2) v = fmaxf(fmaf(v, bnsc, bnbt), 0.f);
      }
      pv[r] = f2bf_fast(v);
    }
    pk.x = pv[0]; pk.y = pv[1]; pk.z = pv[2]; pk.w = pv[3];
    *reinterpret_cast<ushort4*>(oB + pr*PSTO + t*RSTO + colbase) = pk;
  }
}

// ---------------- stage4 (K=192): k-outer / j-inner, swapped ----------------
__device__ __forceinline__ void mfma_stage4(const unsigned short* __restrict__ aB,
    const unsigned short* __restrict__ gW, unsigned short* __restrict__ oB,
    const float* __restrict__ gb0, const float* __restrict__ gb1,
    const float* __restrict__ gb2,
    const int Mtile0, const int Ntile, const int lm, const int lk)
{
  const unsigned short* wbase = gW + (Ntile*16 + lm)*192 + lk*8;
  const int colbase = Ntile*16 + lk*4;
  f32x4 aP[2], aQ[2], aR[2];
  {
    const f32x4 b0v = *reinterpret_cast<const f32x4*>(gb0 + colbase);
    const f32x4 b1v = *reinterpret_cast<const f32x4*>(gb1 + colbase);
    const f32x4 b2v = *reinterpret_cast<const f32x4*>(gb2 + colbase);
    #pragma unroll
    for (int j=0;j<2;++j){ aP[j]=b0v; aQ[j]=b1v; aR[j]=b2v; }
  }
  #pragma unroll 1
  for (int kb = 0; kb < 2; ++kb){
    bf16x8 wp[3], wq[3], wr[3];
    #pragma unroll
    for (int s = 0; s < 3; ++s){
      const int ks = kb*3 + s;
      wp[s] = *reinterpret_cast<const bf16x8*>(wbase +         ks*32);
      wq[s] = *reinterpret_cast<const bf16x8*>(wbase +  6144 + ks*32); // 32*192
      wr[s] = *reinterpret_cast<const bf16x8*>(wbase + 12288 + ks*32);
    }
    #pragma unroll
    for (int j = 0; j < 2; ++j){
      const int m  = (Mtile0 + j*4)*16 + lm;
      const int pr = m >> 2, t = m & 3;
      #pragma unroll
      for (int s = 0; s < 3; ++s){
        const int ks = kb*3 + s;
        const int elem = pr*432 + (t + (ks>>1))*72 + (ks&1)*32 + lk*8;
        const bf16x8 a = *reinterpret_cast<const bf16x8*>(aB + elem);
        aP[j] = __builtin_amdgcn_mfma_f32_16x16x32_bf16(wp[s], a, aP[j], 0,0,0);
        aQ[j] = __builtin_amdgcn_mfma_f32_16x16x32_bf16(wq[s], a, aQ[j], 0,0,0);
        aR[j] = __builtin_amdgcn_mfma_f32_16x16x32_bf16(wr[s], a, aR[j], 0,0,0);
      }
    }
  }
  #pragma unroll
  for (int j = 0; j < 2; ++j){
    const int m  = (Mtile0 + j*4)*16 + lm;
    const int pr = m >> 2, t = m & 3;
    ushort4 pk;
    unsigned short pv[4];
    #pragma unroll
    for (int r = 0; r < 4; ++r){
      const float sig = 1.f/(1.f + __expf(-aQ[j][r]));
      pv[r] = f2bf_fast(fmaxf(fmaf(aP[j][r], sig, aR[j][r]), 0.f));
    }
    pk.x = pv[0]; pk.y = pv[1]; pk.z = pv[2]; pk.w = pv[3];
    *reinterpret_cast<ushort4*>(oB + pr*160 + t*40 + colbase) = pk;
  }
}

// ---------------- main fused kernel ----------------
// LDS: one 48,128 B arena. bufA = smem[0..13823], bufB = smem[13824..24063],
// sxb ALIASES bufB (dead before cheb1 writes bufB).
// launch_bounds(512,4): stage3 preload (~36 held frag regs + acc) lands
// ~60-75 VGPR, r5-proven no-spill. Occupancy ~16 waves/CU (proven non-binding
// r8/r10); the target of this round is the vmem/L1 weight-load pipe.
__global__ __launch_bounds__(NT, 4) void stgcn_main(const Params p,
    const unsigned short* __restrict__ W)
{
  __shared__ __align__(16) unsigned short smem[24064];   // 48,128 B
  unsigned short* const bufA = smem;            // 13824 elems (27648 B)
  unsigned short* const bufB = smem + 13824;    // 10240 elems (20480 B)
  unsigned short* const sxb  = bufB;            // 2816 elems, dead before cheb1

  const int tid = threadIdx.x;
  const int l   = tid & 63;
  const int wid = tid >> 6;     // 0..7
  const int lm  = l & 15;
  const int lk  = l >> 4;
  const int n   = blockIdx.x >> 5;          // b-fastest: 32 consecutive blocks
  const int b0  = (blockIdx.x & 31) * NP;   // share one n (weights L2-hot)

  // x tile: one 8B chunk per (pr, half-slot); even chunks get bf16(x), odd zeros
  for (int i = tid; i < NP*22; i += NT){
    const int pr = i / 22, c = i - pr*22;
    const int t  = c >> 1;
    unsigned short v0=0,v1=0,v2=0,v3=0;
    if (!(c & 1) && t < 10){
      const float4 xf = *reinterpret_cast<const float4*>(
          &p.x[(size_t)(((b0+pr)*10 + t)*113 + n)*4]);
      v0 = f2bf(xf.x); v1 = f2bf(xf.y); v2 = f2bf(xf.z); v3 = f2bf(xf.w);
    }
    ushort4 pk; pk.x=v0; pk.y=v1; pk.z=v2; pk.w=v3;
    *reinterpret_cast<ushort4*>(&sxb[i*4]) = pk;
  }
  __syncthreads();

  // stage1: (10,4)->(8,32) gated conv, K padded 12->32. M=256(16) N=32(2) -> bufA
  mfma_stage<8,32,32,1, 8,88, 40,320, 32, 1, 4,4, false>(
      sxb, W+OFF_S1B, bufA, p.abp, p.abq, p.abr, wid>>1, wid&1, lm, lk, 0.f, 0.f);
  __syncthreads();

  // cheb1: M=256(16) N=32(2) K=32 -> bufB (overwrites sxb region, now dead)
  mfma_stage<8,32,32,1, 40,320, 40,320, 32, 0, 4,4, false>(
      bufA, W+OFF_CHEB_A, bufB, p.acb, p.acb, p.acb, wid>>1, wid&1, lm, lk, 0.f, 0.f);
  __syncthreads();

  // stage3: (8,32)->(6,64) gated + BN(a). M=192(12) N=64(4) K=96 -> bufA
  // PRELOAD: 9 frags loaded once per wave, reused across 6 M-jobs (was the
  // 432-load hotspot with RELOADB).
  {
    const float bnsc = INV_STD * p.ag[n], bnbt = p.abeta[n];
    mfma_stage<6,32,64,3, 40,320, 72,432, 96, 2, 6,2, false>(
        bufB, W+OFF_A2, bufA, p.abp2, p.abq2, p.abr2, wid>>2, wid&3, lm, lk, bnsc, bnbt);
  }
  __syncthreads();

  // stage4: (6,64)->(4,32) gated. M=128(8) N=32(2) K=192 -> bufB
  mfma_stage4(bufA, W+OFF_B1, bufB, p.bbp, p.bbq, p.bbr, wid>>1, wid&1, lm, lk);
  __syncthreads();

  // cheb2: M=128(8) N=32(2) K=32 -> bufA
  mfma_stage<4,32,32,1, 40,160, 40,160, 32, 0, 2,4, false>(
      bufB, W+OFF_CHEB_B, bufA, p.bcb, p.bcb, p.bcb, wid>>1, wid&1, lm, lk, 0.f, 0.f);
  __syncthreads();

  // stage6: (4,32)->(2,16) gated + BN(b). M=64(4) N=16(1) K=96 -> bufB (h4)
  if (wid < 4){
    const float bnsc = INV_STD * p.bg[n], bnbt = p.bbeta[n];
    mfma_stage<2,32,16,3, 40,160, 16,40, 96, 2, 1,1, false>(
        bufA, W+OFF_B2, bufB, p.bbp2, p.bbq2, p.bbr2, wid, 0, lm, lk, bnsc, bnbt);
  }
  __syncthreads();

  // mlp1: feat(32) -> hid(64). M=32(2) N=64(4) K=32 -> bufA
  mfma_stage<1,32,64,1, 16,40, 16,72, 32, 0, 1,1, false>(
      bufB, W+OFF_W1 + n*2048, bufA, p.b1 + n*64, p.b1, p.b1, wid&1, wid>>1, lm, lk, 0.f, 0.f);
  __syncthreads();

  // mlp2: hid(64) -> 3, swapped. C: row=o=lk*4+r, col=m=Mtile*16+lm.
  // Only lk==0, r<3 valid; each such lane stores 3 consecutive f32.
  if (wid < 2){
    const unsigned short* WM2 = W + OFF_W2 + n*192;
    const int Mtile = wid;
    const int m = Mtile*16 + lm;
    const int lmo = (lm < 3) ? lm : 0;       // clamp A-row into valid W2 rows
    f32x4 acc = bcast(0.f);
    if (lk == 0){ acc[0]=p.b2[n*3]; acc[1]=p.b2[n*3+1]; acc[2]=p.b2[n*3+2]; }
    #pragma unroll
    for (int ks = 0; ks < 2; ++ks){
      const bf16x8 aw = *reinterpret_cast<const bf16x8*>(WM2 + lmo*64 + ks*32 + lk*8);
      const bf16x8 bh = *reinterpret_cast<const bf16x8*>(bufA + m*72 + ks*32 + lk*8);
      acc = __builtin_amdgcn_mfma_f32_16x16x32_bf16(aw, bh, acc, 0, 0, 0);
    }
    if (lk == 0){
      float* op = p.out + (size_t)((b0 + m)*113 + n)*3;
      op[0] = acc[0]; op[1] = acc[1]; op[2] = acc[2];
    }
  }
}

} // namespace

extern "C" void kernel_launch(void* const* d_in, const int* in_sizes, int n_in,
                              void* d_out, int out_size, void* d_ws, size_t ws_size,
                              hipStream_t stream) {
  (void)in_sizes; (void)n_in; (void)ws_size; (void)out_size;
  Params p;
  p.x     = (const float*)d_in[0];
  // d_in[1] = edge_index (unused: ChebConv K=1 keeps only the identity term)
  p.awp   = (const float*)d_in[2];  p.abp   = (const float*)d_in[3];
  p.awq   = (const float*)d_in[4];  p.abq   = (const float*)d_in[5];
  p.awr   = (const float*)d_in[6];  p.abr   = (const float*)d_in[7];
  p.acw   = (const float*)d_in[8];  p.acb   = (const float*)d_in[9];
  p.awp2  = (const float*)d_in[10]; p.abp2  = (const float*)d_in[11];
  p.awq2  = (const float*)d_in[12]; p.abq2  = (const float*)d_in[13];
  p.awr2  = (const float*)d_in[14]; p.abr2  = (const float*)d_in[15];
  p.ag    = (const float*)d_in[16]; p.abeta = (const float*)d_in[17];
  p.bwp   = (const float*)d_in[18]; p.bbp   = (const float*)d_in[19];
  p.bwq   = (const float*)d_in[20]; p.bbq   = (const float*)d_in[21];
  p.bwr   = (const float*)d_in[22]; p.bbr   = (const float*)d_in[23];
  p.bcw   = (const float*)d_in[24]; p.bcb   = (const float*)d_in[25];
  p.bwp2  = (const float*)d_in[26]; p.bbp2  = (const float*)d_in[27];
  p.bwq2  = (const float*)d_in[28]; p.bbq2  = (const float*)d_in[29];
  p.bwr2  = (const float*)d_in[30]; p.bbr2  = (const float*)d_in[31];
  p.bg    = (const float*)d_in[32]; p.bbeta = (const float*)d_in[33];
  p.w1    = (const float*)d_in[34]; p.b1    = (const float*)d_in[35];
  p.w2    = (const float*)d_in[36]; p.b2    = (const float*)d_in[37];
  p.out   = (float*)d_out;

  unsigned short* W = (unsigned short*)d_ws;   // needs 599,424 bytes

  // prep: 299,712 work items
  stgcn_prep<<<1171, 256, 0, stream>>>(p, W);

  const int tiles = 113 * 32;  // 3616, b fastest within each n
  stgcn_main<<<tiles, NT, 0, stream>>>(p, W);
}

// Round 14
// 145.315 us; speedup vs baseline: 1.3845x; 1.0034x over previous
//
#include <hip/hip_runtime.h>
#include <hip/hip_bf16.h>
#include <math.h>

// STGCN fused, MFMA version, round 14: 2-way M-job ILP.
// Round 13 falsified the L1-weight-load theory (cutting 432->72 loads made it
// SLOWER). Remaining model: latency-bound with too little ILP per wave -
// unroll-1 M-jobs serialize {ds_read ~120cy -> MFMA -> trans-heavy epilogue}.
// This round pairs M-jobs: two independent accumulator sets, interleaved
// MFMA chains, paired epilogues (8 independent exp/rcp chains hide the
// quarter-rate transcendental latency). RELOADB frags load once per k-step,
// shared by both jobs. launch_bounds(512,4) for the +~30 reg live set.
// Everything else identical to round 11 (138.7us best).

namespace {

constexpr int NT = 512;               // 8 waves
constexpr int NP = 32;                // (b,n) pairs per block (same n)
constexpr float INV_STD = 0.9999950000374997f; // 1/sqrt(1+1e-5)

typedef __attribute__((ext_vector_type(8))) short bf16x8;
typedef __attribute__((ext_vector_type(4))) float f32x4;

// d_ws layout (bf16 element offsets). All sections 16B-aligned (off%8==0).
constexpr int OFF_CHEB_A = 0;         // [32co][32k]
constexpr int OFF_CHEB_B = 1024;      // [32co][32k]
constexpr int OFF_A2     = 2048;      // P,Q,R x [64co][96k]
constexpr int OFF_B1     = 20480;     // P,Q,R x [32co][192k]
constexpr int OFF_B2     = 38912;     // P,Q,R x [16co][96k]
constexpr int OFF_S1B    = 43520;     // P,Q,R x [32co][32k] (zero-padded K)
constexpr int OFF_W1     = 46592;     // 113 x [64h][32k]
constexpr int OFF_W2     = 278016;    // 113 x [3o][64k]
// total ws bytes needed: (278016 + 21696) * 2 = 599,424

__device__ __forceinline__ unsigned short f2bf(float f){   // RNE f32->bf16 (prep)
  unsigned int u = __float_as_uint(f);
  u += 0x7fffu + ((u >> 16) & 1u);
  return (unsigned short)(u >> 16);
}
__device__ __forceinline__ unsigned short f2bf_fast(float f){  // native RNE
  return __bfloat16_as_ushort(__float2bfloat16(f));
}
__device__ __forceinline__ f32x4 bcast(float v){ f32x4 r; r[0]=v; r[1]=v; r[2]=v; r[3]=v; return r; }

struct Params {
  const float *x;
  const float *awp,*abp,*awq,*abq,*awr,*abr,*acw,*acb;
  const float *awp2,*abp2,*awq2,*abq2,*awr2,*abr2,*ag,*abeta;
  const float *bwp,*bbp,*bwq,*bbq,*bwr,*bbr,*bcw,*bcb;
  const float *bwp2,*bbp2,*bwq2,*bbq2,*bwr2,*bbr2,*bg,*bbeta;
  const float *w1,*b1,*w2,*b2;
  float *out;
};

// ---------------- prep: one-time weight transpose/convert into ws ----------------
__global__ void stgcn_prep(const Params p, unsigned short* __restrict__ W)
{
  int e = blockIdx.x*256 + threadIdx.x;
  if (e < 2048){                                    // cheb a/b [ci][co] -> [co][ci]
    const float* src = (e < 1024) ? p.acw : p.bcw;
    const int j = e & 1023, co = j >> 5, k = j & 31;
    W[e] = f2bf(src[k*32 + co]);
    return;
  }
  e -= 2048;
  if (e < 18432){                                   // a2: 3 x [64co][96k]
    const int mat = e / 6144, j = e % 6144, co = j / 96, k = j % 96;
    const float* src = mat==0 ? p.awp2 : (mat==1 ? p.awq2 : p.awr2);
    W[OFF_A2 + e] = f2bf(src[k*64 + co]);
    return;
  }
  e -= 18432;
  if (e < 18432){                                   // b1: 3 x [32co][192k]
    const int mat = e / 6144, j = e % 6144, co = j / 192, k = j % 192;
    const float* src = mat==0 ? p.bwp : (mat==1 ? p.bwq : p.bwr);
    W[OFF_B1 + e] = f2bf(src[k*32 + co]);
    return;
  }
  e -= 18432;
  if (e < 4608){                                    // b2: 3 x [16co][96k]
    const int mat = e / 1536, j = e % 1536, co = j / 96, k = j % 96;
    const float* src = mat==0 ? p.bwp2 : (mat==1 ? p.bwq2 : p.bwr2);
    W[OFF_B2 + e] = f2bf(src[k*16 + co]);
    return;
  }
  e -= 4608;
  if (e < 3072){                                    // s1: 3 x [32co][32k], k=tt*8+ci
    const int mat = e / 1024, j = e % 1024, co = j >> 5, k = j & 31;
    const int tt = k >> 3, ci = k & 7;
    const float* src = mat==0 ? p.awp : (mat==1 ? p.awq : p.awr);
    W[OFF_S1B + e] = (ci < 4 && tt < 3) ? f2bf(src[(tt*4+ci)*32 + co])
                                        : (unsigned short)0;
    return;
  }
  e -= 3072;
  if (e < 231424){ W[OFF_W1 + e] = f2bf(p.w1[e]); return; }  // [n][h][f] already B^T
  e -= 231424;
  if (e < 21696){ W[OFF_W2 + e] = f2bf(p.w2[e]); }           // [n][o][k] already B^T
}

// ---------------- generic MFMA stage (operand-swapped, 2-way M-job ILP) ----------------
// Weights are the A operand (row = co), activations are B (col = m).
// C: lane holds co = Ntile*16 + lk*4 + r (4 consecutive) for ONE m ->
// epilogue is a single ushort4 store + float4 bias init.
// M-jobs processed in PAIRS: two independent accumulator sets, interleaved
// MFMA chains, paired epilogues (independent exp/rcp chains overlap).
// EPI: 0 = relu(acc+bias); 1 = relu(P*sig(Q)+R); 2 = EPI1 then relu(v*bn+bt).
template<int TOUT, int CIN, int COUT, int NK, int RSTI, int PSTI, int RSTO, int PSTO,
         int KP, int EPI, int MJOBS, int MSTEP, bool RELOADB>
__device__ __forceinline__ void mfma_stage(const unsigned short* __restrict__ aB,
    const unsigned short* __restrict__ gW, unsigned short* __restrict__ oB,
    const float* __restrict__ gb0, const float* __restrict__ gb1,
    const float* __restrict__ gb2,
    const int Mtile0, const int Ntile, const int lm, const int lk,
    const float bnsc, const float bnbt)
{
  const unsigned short* wbase = gW + (Ntile*16 + lm)*KP + lk*8;
  const int colbase = Ntile*16 + lk*4;      // this lane's 4 output channels
  bf16x8 wp[NK], wq[NK], wr[NK];
  if constexpr (!RELOADB){
    #pragma unroll
    for (int ks = 0; ks < NK; ++ks){
      wp[ks] = *reinterpret_cast<const bf16x8*>(wbase + ks*32);
      if constexpr (EPI >= 1){
        wq[ks] = *reinterpret_cast<const bf16x8*>(wbase +   COUT*KP + ks*32);
        wr[ks] = *reinterpret_cast<const bf16x8*>(wbase + 2*COUT*KP + ks*32);
      }
    }
  }
  const f32x4 b0v = *reinterpret_cast<const f32x4*>(gb0 + colbase);
  f32x4 b1v = b0v, b2v = b0v;
  if constexpr (EPI >= 1){
    b1v = *reinterpret_cast<const f32x4*>(gb1 + colbase);
    b2v = *reinterpret_cast<const f32x4*>(gb2 + colbase);
  }

  auto aelem = [&](const int m, const int ks) -> int {
    const int pr = m / TOUT;
    const int t  = m - pr*TOUT;
    if constexpr (CIN == 32) return pr*PSTI + (t + ks)*RSTI + lk*8;
    else                     return pr*PSTI + (t + (ks>>1))*RSTI + (ks&1)*32 + lk*8;
  };
  auto epi = [&](const f32x4 aP, const f32x4 aQ, const f32x4 aR, const int m){
    const int pr = m / TOUT;
    const int t  = m - pr*TOUT;
    unsigned short pv[4];
    #pragma unroll
    for (int r = 0; r < 4; ++r){
      float v;
      if constexpr (EPI == 0) v = fmaxf(aP[r], 0.f);
      else {
        const float sig = 1.f/(1.f + __expf(-aQ[r]));
        v = fmaxf(fmaf(aP[r], sig, aR[r]), 0.f);
        if constexpr (EPI == 2) v = fmaxf(fmaf(v, bnsc, bnbt), 0.f);
      }
      pv[r] = f2bf_fast(v);
    }
    ushort4 pk; pk.x = pv[0]; pk.y = pv[1]; pk.z = pv[2]; pk.w = pv[3];
    *reinterpret_cast<ushort4*>(oB + pr*PSTO + t*RSTO + colbase) = pk;
  };

  // ---- paired M-jobs: 2 independent chains in flight ----
  #pragma unroll 1
  for (int jj = 0; jj < MJOBS/2; ++jj){
    const int m0 = (Mtile0 + (2*jj  )*MSTEP)*16 + lm;
    const int m1 = (Mtile0 + (2*jj+1)*MSTEP)*16 + lm;
    f32x4 aP0 = b0v, aP1 = b0v, aQ0 = b1v, aQ1 = b1v, aR0 = b2v, aR1 = b2v;
    #pragma unroll
    for (int ks = 0; ks < NK; ++ks){
      bf16x8 fp, fq, fr;
      if constexpr (RELOADB){
        fp = *reinterpret_cast<const bf16x8*>(wbase + ks*32);
        if constexpr (EPI >= 1){
          fq = *reinterpret_cast<const bf16x8*>(wbase +   COUT*KP + ks*32);
          fr = *reinterpret_cast<const bf16x8*>(wbase + 2*COUT*KP + ks*32);
        }
      } else {
        fp = wp[ks];
        if constexpr (EPI >= 1){ fq = wq[ks]; fr = wr[ks]; }
      }
      const bf16x8 a0 = *reinterpret_cast<const bf16x8*>(aB + aelem(m0, ks));
      const bf16x8 a1 = *reinterpret_cast<const bf16x8*>(aB + aelem(m1, ks));
      aP0 = __builtin_amdgcn_mfma_f32_16x16x32_bf16(fp, a0, aP0, 0, 0, 0);
      aP1 = __builtin_amdgcn_mfma_f32_16x16x32_bf16(fp, a1, aP1, 0, 0, 0);
      if constexpr (EPI >= 1){
        aQ0 = __builtin_amdgcn_mfma_f32_16x16x32_bf16(fq, a0, aQ0, 0, 0, 0);
        aQ1 = __builtin_amdgcn_mfma_f32_16x16x32_bf16(fq, a1, aQ1, 0, 0, 0);
        aR0 = __builtin_amdgcn_mfma_f32_16x16x32_bf16(fr, a0, aR0, 0, 0, 0);
        aR1 = __builtin_amdgcn_mfma_f32_16x16x32_bf16(fr, a1, aR1, 0, 0, 0);
      }
    }
    epi(aP0, aQ0, aR0, m0);
    epi(aP1, aQ1, aR1, m1);
  }
  // ---- odd tail ----
  if constexpr (MJOBS & 1){
    const int m0 = (Mtile0 + (MJOBS-1)*MSTEP)*16 + lm;
    f32x4 aP0 = b0v, aQ0 = b1v, aR0 = b2v;
    #pragma unroll
    for (int ks = 0; ks < NK; ++ks){
      bf16x8 fp, fq, fr;
      if constexpr (RELOADB){
        fp = *reinterpret_cast<const bf16x8*>(wbase + ks*32);
        if constexpr (EPI >= 1){
          fq = *reinterpret_cast<const bf16x8*>(wbase +   COUT*KP + ks*32);
          fr = *reinterpret_cast<const bf16x8*>(wbase + 2*COUT*KP + ks*32);
        }
      } else {
        fp = wp[ks];
        if constexpr (EPI >= 1){ fq = wq[ks]; fr = wr[ks]; }
      }
      const bf16x8 a0 = *reinterpret_cast<const bf16x8*>(aB + aelem(m0, ks));
      aP0 = __builtin_amdgcn_mfma_f32_16x16x32_bf16(fp, a0, aP0, 0, 0, 0);
      if constexpr (EPI >= 1){
        aQ0 = __builtin_amdgcn_mfma_f32_16x16x32_bf16(fq, a0, aQ0, 0, 0, 0);
        aR0 = __builtin_amdgcn_mfma_f32_16x16x32_bf16(fr, a0, aR0, 0, 0, 0);
      }
    }
    epi(aP0, aQ0, aR0, m0);
  }
}

// ---------------- stage4 (K=192): k-outer / j-inner, swapped (r11) ----------------
__device__ __forceinline__ void mfma_stage4(const unsigned short* __restrict__ aB,
    const unsigned short* __restrict__ gW, unsigned short* __restrict__ oB,
    const float* __restrict__ gb0, const float* __restrict__ gb1,
    const float* __restrict__ gb2,
    const int Mtile0, const int Ntile, const int lm, const int lk)
{
  const unsigned short* wbase = gW + (Ntile*16 + lm)*192 + lk*8;
  const int colbase = Ntile*16 + lk*4;
  f32x4 aP[2], aQ[2], aR[2];
  {
    const f32x4 b0v = *reinterpret_cast<const f32x4*>(gb0 + colbase);
    const f32x4 b1v = *reinterpret_cast<const f32x4*>(gb1 + colbase);
    const f32x4 b2v = *reinterpret_cast<const f32x4*>(gb2 + colbase);
    #pragma unroll
    for (int j=0;j<2;++j){ aP[j]=b0v; aQ[j]=b1v; aR[j]=b2v; }
  }
  #pragma unroll 1
  for (int kb = 0; kb < 2; ++kb){
    bf16x8 wp[3], wq[3], wr[3];
    #pragma unroll
    for (int s = 0; s < 3; ++s){
      const int ks = kb*3 + s;
      wp[s] = *reinterpret_cast<const bf16x8*>(wbase +         ks*32);
      wq[s] = *reinterpret_cast<const bf16x8*>(wbase +  6144 + ks*32); // 32*192
      wr[s] = *reinterpret_cast<const bf16x8*>(wbase + 12288 + ks*32);
    }
    #pragma unroll
    for (int j = 0; j < 2; ++j){
      const int m  = (Mtile0 + j*4)*16 + lm;
      const int pr = m >> 2, t = m & 3;
      #pragma unroll
      for (int s = 0; s < 3; ++s){
        const int ks = kb*3 + s;
        const int elem = pr*432 + (t + (ks>>1))*72 + (ks&1)*32 + lk*8;
        const bf16x8 a = *reinterpret_cast<const bf16x8*>(aB + elem);
        aP[j] = __builtin_amdgcn_mfma_f32_16x16x32_bf16(wp[s], a, aP[j], 0,0,0);
        aQ[j] = __builtin_amdgcn_mfma_f32_16x16x32_bf16(wq[s], a, aQ[j], 0,0,0);
        aR[j] = __builtin_amdgcn_mfma_f32_16x16x32_bf16(wr[s], a, aR[j], 0,0,0);
      }
    }
  }
  #pragma unroll
  for (int j = 0; j < 2; ++j){
    const int m  = (Mtile0 + j*4)*16 + lm;
    const int pr = m >> 2, t = m & 3;
    ushort4 pk;
    unsigned short pv[4];
    #pragma unroll
    for (int r = 0; r < 4; ++r){
      const float sig = 1.f/(1.f + __expf(-aQ[j][r]));
      pv[r] = f2bf_fast(fmaxf(fmaf(aP[j][r], sig, aR[j][r]), 0.f));
    }
    pk.x = pv[0]; pk.y = pv[1]; pk.z = pv[2]; pk.w = pv[3];
    *reinterpret_cast<ushort4*>(oB + pr*160 + t*40 + colbase) = pk;
  }
}

// ---------------- main fused kernel ----------------
// LDS: one 48,128 B arena. bufA = smem[0..13823], bufB = smem[13824..24063],
// sxb ALIASES bufB (dead before cheb1 writes bufB).
// launch_bounds(512,4): paired accumulators land ~80-100 VGPR, no spill.
__global__ __launch_bounds__(NT, 4) void stgcn_main(const Params p,
    const unsigned short* __restrict__ W)
{
  __shared__ __align__(16) unsigned short smem[24064];   // 48,128 B
  unsigned short* const bufA = smem;            // 13824 elems (27648 B)
  unsigned short* const bufB = smem + 13824;    // 10240 elems (20480 B)
  unsigned short* const sxb  = bufB;            // 2816 elems, dead before cheb1

  const int tid = threadIdx.x;
  const int l   = tid & 63;
  const int wid = tid >> 6;     // 0..7
  const int lm  = l & 15;
  const int lk  = l >> 4;
  const int n   = blockIdx.x >> 5;          // b-fastest: 32 consecutive blocks
  const int b0  = (blockIdx.x & 31) * NP;   // share one n (weights L2-hot)

  // x tile: one 8B chunk per (pr, half-slot); even chunks get bf16(x), odd zeros
  for (int i = tid; i < NP*22; i += NT){
    const int pr = i / 22, c = i - pr*22;
    const int t  = c >> 1;
    unsigned short v0=0,v1=0,v2=0,v3=0;
    if (!(c & 1) && t < 10){
      const float4 xf = *reinterpret_cast<const float4*>(
          &p.x[(size_t)(((b0+pr)*10 + t)*113 + n)*4]);
      v0 = f2bf(xf.x); v1 = f2bf(xf.y); v2 = f2bf(xf.z); v3 = f2bf(xf.w);
    }
    ushort4 pk; pk.x=v0; pk.y=v1; pk.z=v2; pk.w=v3;
    *reinterpret_cast<ushort4*>(&sxb[i*4]) = pk;
  }
  __syncthreads();

  // stage1: (10,4)->(8,32) gated conv, K padded 12->32. M=256(16) N=32(2) -> bufA
  mfma_stage<8,32,32,1, 8,88, 40,320, 32, 1, 4,4, false>(
      sxb, W+OFF_S1B, bufA, p.abp, p.abq, p.abr, wid>>1, wid&1, lm, lk, 0.f, 0.f);
  __syncthreads();

  // cheb1: M=256(16) N=32(2) K=32 -> bufB (overwrites sxb region, now dead)
  mfma_stage<8,32,32,1, 40,320, 40,320, 32, 0, 4,4, false>(
      bufA, W+OFF_CHEB_A, bufB, p.acb, p.acb, p.acb, wid>>1, wid&1, lm, lk, 0.f, 0.f);
  __syncthreads();

  // stage3: (8,32)->(6,64) gated + BN(a). M=192(12) N=64(4) K=96 -> bufA
  // RELOADB: frags loaded once per k-step, shared by the job pair.
  {
    const float bnsc = INV_STD * p.ag[n], bnbt = p.abeta[n];
    mfma_stage<6,32,64,3, 40,320, 72,432, 96, 2, 6,2, true>(
        bufB, W+OFF_A2, bufA, p.abp2, p.abq2, p.abr2, wid>>2, wid&3, lm, lk, bnsc, bnbt);
  }
  __syncthreads();

  // stage4: (6,64)->(4,32) gated. M=128(8) N=32(2) K=192 -> bufB
  mfma_stage4(bufA, W+OFF_B1, bufB, p.bbp, p.bbq, p.bbr, wid>>1, wid&1, lm, lk);
  __syncthreads();

  // cheb2: M=128(8) N=32(2) K=32 -> bufA
  mfma_stage<4,32,32,1, 40,160, 40,160, 32, 0, 2,4, false>(
      bufB, W+OFF_CHEB_B, bufA, p.bcb, p.bcb, p.bcb, wid>>1, wid&1, lm, lk, 0.f, 0.f);
  __syncthreads();

  // stage6: (4,32)->(2,16) gated + BN(b). M=64(4) N=16(1) K=96 -> bufB (h4)
  if (wid < 4){
    const float bnsc = INV_STD * p.bg[n], bnbt = p.bbeta[n];
    mfma_stage<2,32,16,3, 40,160, 16,40, 96, 2, 1,1, false>(
        bufA, W+OFF_B2, bufB, p.bbp2, p.bbq2, p.bbr2, wid, 0, lm, lk, bnsc, bnbt);
  }
  __syncthreads();

  // mlp1: feat(32) -> hid(64). M=32(2) N=64(4) K=32 -> bufA
  mfma_stage<1,32,64,1, 16,40, 16,72, 32, 0, 1,1, false>(
      bufB, W+OFF_W1 + n*2048, bufA, p.b1 + n*64, p.b1, p.b1, wid&1, wid>>1, lm, lk, 0.f, 0.f);
  __syncthreads();

  // mlp2: hid(64) -> 3, swapped. C: row=o=lk*4+r, col=m=Mtile*16+lm.
  // Only lk==0, r<3 valid; each such lane stores 3 consecutive f32.
  if (wid < 2){
    const unsigned short* WM2 = W + OFF_W2 + n*192;
    const int Mtile = wid;
    const int m = Mtile*16 + lm;
    const int lmo = (lm < 3) ? lm : 0;       // clamp A-row into valid W2 rows
    f32x4 acc = bcast(0.f);
    if (lk == 0){ acc[0]=p.b2[n*3]; acc[1]=p.b2[n*3+1]; acc[2]=p.b2[n*3+2]; }
    #pragma unroll
    for (int ks = 0; ks < 2; ++ks){
      const bf16x8 aw = *reinterpret_cast<const bf16x8*>(WM2 + lmo*64 + ks*32 + lk*8);
      const bf16x8 bh = *reinterpret_cast<const bf16x8*>(bufA + m*72 + ks*32 + lk*8);
      acc = __builtin_amdgcn_mfma_f32_16x16x32_bf16(aw, bh, acc, 0, 0, 0);
    }
    if (lk == 0){
      float* op = p.out + (size_t)((b0 + m)*113 + n)*3;
      op[0] = acc[0]; op[1] = acc[1]; op[2] = acc[2];
    }
  }
}

} // namespace

extern "C" void kernel_launch(void* const* d_in, const int* in_sizes, int n_in,
                              void* d_out, int out_size, void* d_ws, size_t ws_size,
                              hipStream_t stream) {
  (void)in_sizes; (void)n_in; (void)d_ws; (void)ws_size; (void)out_size;
  Params p;
  p.x     = (const float*)d_in[0];
  // d_in[1] = edge_index (unused: ChebConv K=1 keeps only the identity term)
  p.awp   = (const float*)d_in[2];  p.abp   = (const float*)d_in[3];
  p.awq   = (const float*)d_in[4];  p.abq   = (const float*)d_in[5];
  p.awr   = (const float*)d_in[6];  p.abr   = (const float*)d_in[7];
  p.acw   = (const float*)d_in[8];  p.acb   = (const float*)d_in[9];
  p.awp2  = (const float*)d_in[10]; p.abp2  = (const float*)d_in[11];
  p.awq2  = (const float*)d_in[12]; p.abq2  = (const float*)d_in[13];
  p.awr2  = (const float*)d_in[14]; p.abr2  = (const float*)d_in[15];
  p.ag    = (const float*)d_in[16]; p.abeta = (const float*)d_in[17];
  p.bwp   = (const float*)d_in[18]; p.bbp   = (const float*)d_in[19];
  p.bwq   = (const float*)d_in[20]; p.bbq   = (const float*)d_in[21];
  p.bwr   = (const float*)d_in[22]; p.bbr   = (const float*)d_in[23];
  p.bcw   = (const float*)d_in[24]; p.bcb   = (const float*)d_in[25];
  p.bwp2  = (const float*)d_in[26]; p.bbp2  = (const float*)d_in[27];
  p.bwq2  = (const float*)d_in[28]; p.bbq2  = (const float*)d_in[29];
  p.bwr2  = (const float*)d_in[30]; p.bbr2  = (const float*)d_in[31];
  p.bg    = (const float*)d_in[32]; p.bbeta = (const float*)d_in[33];
  p.w1    = (const float*)d_in[34]; p.b1    = (const float*)d_in[35];
  p.w2    = (const float*)d_in[36]; p.b2    = (const float*)d_in[37];
  p.out   = (float*)d_out;

  unsigned short* W = (unsigned short*)d_ws;   // needs 599,424 bytes

  // prep: 299,712 work items
  stgcn_prep<<<1171, 256, 0, stream>>>(p, W);

  const int tiles = 113 * 32;  // 3616, b fastest within each n
  stgcn_main<<<tiles, NT, 0, stream>>>(p, W);
}